// Round 10
// baseline (3892.953 us; speedup 1.0000x reference)
//
#include <hip/hip_runtime.h>
#include <math.h>

#define NBLK 1024
#define NTHR 256

typedef float vf4 __attribute__((ext_vector_type(4)));

namespace spinn {

constexpr int Ss = 48, Hh = 256, TT = 96, Mm = 193, H3 = 768, MLPD = 1024;
constexpr int Mp = 200;   // padded stack rows (8 mg-groups x 25)

__device__ __forceinline__ float sigf(float x) { return 1.0f / (1.0f + expf(-x)); }

#define FMA4(acc, a, b)                         \
    {                                           \
        acc.x = fmaf((a).x, (b).x, acc.x);      \
        acc.y = fmaf((a).y, (b).y, acc.y);      \
        acc.z = fmaf((a).z, (b).z, acc.z);      \
        acc.w = fmaf((a).w, (b).w, acc.w);      \
    }

// ---- coherent (device-scope) access helpers ----
__device__ __forceinline__ void st_co(float* p, float v) {
    asm volatile("global_store_dword %0, %1, off sc0 sc1" :: "v"(p), "v"(v) : "memory");
}
__device__ __forceinline__ void ld_co_v4_1(const vf4* p0, vf4& r0) {
    asm volatile("global_load_dwordx4 %0, %1, off sc0 sc1\n\t"
                 "s_waitcnt vmcnt(0)"
                 : "=&v"(r0) : "v"(p0) : "memory");
}
__device__ __forceinline__ void ld_co_f1x4(const float* p0, const float* p1, const float* p2,
                                           const float* p3, float& r0, float& r1, float& r2, float& r3) {
    asm volatile("global_load_dword %0, %4, off sc0 sc1\n\t"
                 "global_load_dword %1, %5, off sc0 sc1\n\t"
                 "global_load_dword %2, %6, off sc0 sc1\n\t"
                 "global_load_dword %3, %7, off sc0 sc1\n\t"
                 "s_waitcnt vmcnt(0)"
                 : "=&v"(r0), "=&v"(r1), "=&v"(r2), "=&v"(r3)
                 : "v"(p0), "v"(p1), "v"(p2), "v"(p3) : "memory");
}
__device__ __forceinline__ unsigned ld_co_u32(const unsigned* p) {
    unsigned r;
    asm volatile("global_load_dword %0, %1, off sc0 sc1\n\t"
                 "s_waitcnt vmcnt(0)"
                 : "=&v"(r) : "v"(p) : "memory");
    return r;
}

// ---- per-group (32-block) barrier ----
__device__ __forceinline__ void gbar(unsigned* cnt, unsigned tgt) {
    asm volatile("s_waitcnt vmcnt(0)" ::: "memory");
    __syncthreads();
    if (threadIdx.x == 0) {
        unsigned one = 1u;
        asm volatile("global_atomic_add %0, %1, off" :: "v"(cnt), "v"(one) : "memory");
        while (ld_co_u32(cnt) < tgt) __builtin_amdgcn_s_sleep(1);
    }
    __syncthreads();
}

// ---- wave-level primitives ----
__device__ __forceinline__ float wave_iscan(float v, int lane) {
    #pragma unroll
    for (int off = 1; off < 64; off <<= 1) {
        float u = __shfl_up(v, off, 64);
        if (lane >= off) v += u;
    }
    return v;
}
__device__ __forceinline__ float wred64(float v) {
    #pragma unroll
    for (int off = 1; off < 64; off <<= 1) v += __shfl_xor(v, off, 64);
    return v;
}
__device__ __forceinline__ float wred_mg(float v) {  // reduce over lane bits 3,4,5
    v += __shfl_xor(v, 8, 64);
    v += __shfl_xor(v, 16, 64);
    v += __shfl_xor(v, 32, 64);
    return v;
}

}  // namespace spinn

using namespace spinn;

// Block (ep, q8): element PAIR ep = bid>>5 (elements 2ep,2ep+1), 8-dim slice
// q8 = bid&31.  Same shape/occupancy/independence as the round-7 kernel
// (1024 x 256thr, 4 blocks/CU), but every weight vf4 is loaded ONCE and FMA'd
// against BOTH elements -> chip-wide L2 weight traffic halves.
__global__ void __launch_bounds__(NTHR, 4) spinn_kernel(
    const int* __restrict__ x, const float* __restrict__ emb,
    const float* __restrict__ wih, const float* __restrict__ whh,
    const float* __restrict__ bih, const float* __restrict__ bhh,
    const float* __restrict__ aw, const float* __restrict__ ab,
    const float* __restrict__ tlw, const float* __restrict__ tlb,
    const float* __restrict__ trw, const float* __restrict__ trb,
    const float* __restrict__ l0w, const float* __restrict__ l0b,
    const float* __restrict__ l1w, const float* __restrict__ l1b,
    const float* __restrict__ l2w, const float* __restrict__ l2b,
    float* __restrict__ out, float* __restrict__ wsf, unsigned* __restrict__ bar)
{
    const int tid  = threadIdx.x;
    const int bid  = blockIdx.x;
    const int ep   = bid >> 5;        // element pair 0..31 (= group)
    const int q8   = bid & 31;        // 8-dim slice
    const int db   = q8 * 8;
    const int e0   = ep * 2;
    const int wave = tid >> 6;        // 0..3
    const int lane = tid & 63;
    const int mg   = lane >> 3;       // 8 groups
    const int dl8  = lane & 7;

    unsigned* cnt = bar + ep * 32;    // per-group counter, 128B apart
    unsigned barnum = 0;

    // ---- global workspace (exchange buffers only) ----
    float* XTg = wsf;                 // [64][768]
    float* Hbg = XTg + 64 * H3;       // [64][256]
    float* R1g = Hbg + 64 * Hh;       // [64][256]
    float* R2g = R1g + 64 * Hh;       // [64][256]
    float* Y0g = R2g + 64 * Hh;       // [64][1024]
    float* Y1g = Y0g + 64 * MLPD;     // [64][1024]

    // ---- LDS (~38 KB) ----
    __shared__ float s_V[2 * Mp * 8];    // V stack slices [el][200 m][8 d]
    __shared__ float s_B[2 * Ss * 8];    // embedding slices [el][48][8]
    __shared__ float s_xt[2 * H3];       // staged full xt per element
    __shared__ float s_h[2 * 256];       // staged full h (T1 -> next L)
    __shared__ float s_c[16];            // [el][8] cell state
    __shared__ float s_g[64];            // LSTM preacts [el][32]
    __shared__ float s_tg[80];           // tree preacts [el][40]
    __shared__ float s_r1[2 * 256], s_r2[2 * 256];  // staged full r1/r2
    __shared__ float s_s[2 * Mp];        // stack strengths
    __shared__ float sw1[2 * Mp], sw2[2 * Mp];      // pop weights (pads zero)
    __shared__ float pw1[2 * Mp], pw2[2 * Mp];      // push weights (FULL)
    __shared__ float s_sb[2 * Ss], s_wb[2 * Ss], s_wbe[2 * Ss];
    __shared__ float s_bias[32];         // bih+bhh own rows
    __shared__ float s_tbias[40];        // tlb+trb own rows

    float* s_y = s_V;                    // MLP staging alias (V dead after loop)

    // ================= INIT =================
    {
        if (tid < 192) {              // s_B gather: 2 el x 48 tok x 2 vf4
            int el = tid / 96, r = tid % 96;
            int s = r >> 1, j = r & 1;
            int tok = x[(e0 + el) * Ss + s];
            ((vf4*)s_B)[el * 96 + s * 2 + j] = ((const vf4*)emb)[(size_t)tok * 64 + q8 * 2 + j];
        }
        if (tid < 2 * Ss) {
            int el = tid / Ss, s = tid % Ss;
            s_sb[tid] = (x[(e0 + el) * Ss + s] > 0) ? 1.0f : 0.0f;
        }
        for (int i = tid; i < 2 * Mp; i += NTHR) s_s[i] = 0.0f;
        for (int i = tid; i < 2 * 256; i += NTHR) s_h[i] = 0.0f;
        if (tid < 16) s_c[tid] = 0.0f;
        if (tid < 32) {
            int row = (tid >> 3) * Hh + db + (tid & 7);
            s_bias[tid] = bih[row] + bhh[row];
        }
        if (tid < 40) {
            int row = (tid >> 3) * Hh + db + (tid & 7);
            s_tbias[tid] = tlb[row] + trb[row];
        }
        for (int i = tid; i < 2 * Mp * 8; i += NTHR) s_V[i] = 0.0f;
        __syncthreads();
        if (wave < 2) {               // initial x_b per element (wave = el)
            int el = wave;
            float sbv = (lane < Ss) ? s_sb[el * Ss + lane] : 0.0f;
            float P = wave_iscan(sbv, lane);
            float wbe = fminf(P, 1.0f) - fminf(P - sbv, 1.0f);
            if (lane < Ss) s_wbe[el * Ss + lane] = wbe;
            float axb = 0.0f;
            #pragma unroll
            for (int j = 0; j < 6; j++) {
                int s = mg * 6 + j;
                axb = fmaf(s_wbe[el * Ss + s], s_B[el * 384 + s * 8 + dl8], axb);
            }
            axb = wred_mg(axb);
            if (lane < 8) {
                float* xte = XTg + (size_t)(e0 + el) * H3;
                st_co(xte + db + dl8, axb);
                st_co(xte + 256 + db + dl8, 0.0f);
                st_co(xte + 512 + db + dl8, 0.0f);
            }
        }
    }
    gbar(cnt, ++barnum * 32);

    // ================= time loop =================
    for (int t = 0; t < TT; t++) {
        const int idx  = 191 - 2 * t;
        const int idx2 = idx - 1;

        // ---------- Phase L: stage xt (both el), dual-element LSTM matvec ----------
        {
            for (int i = tid; i < 384; i += NTHR) {
                int el = i / 192, r = i % 192;
                vf4 v;
                ld_co_v4_1((const vf4*)XTg + (size_t)(e0 + el) * 192 + r, v);
                ((vf4*)s_xt)[el * 192 + r] = v;
            }
            __syncthreads();
            const vf4* sxt4 = (const vf4*)s_xt;
            const vf4* sh4  = (const vf4*)s_h;
            vf4 xa0 = sxt4[lane], xa1 = sxt4[64 + lane], xa2 = sxt4[128 + lane];
            vf4 xb0 = sxt4[192 + lane], xb1 = sxt4[256 + lane], xb2 = sxt4[320 + lane];
            vf4 ha = sh4[lane], hb = sh4[64 + lane];
            #pragma unroll 2
            for (int p = 0; p < 8; p++) {
                int r = wave * 8 + p;                     // 32 rows over 4 waves
                int row = ((r >> 3) << 8) + db + (r & 7); // gate*256 + db + d
                const vf4* w  = (const vf4*)wih + (size_t)row * 192;
                const vf4* wh = (const vf4*)whh + (size_t)row * 64;
                vf4 w0 = w[lane], w1 = w[64 + lane], w2 = w[128 + lane], w3 = wh[lane];
                vf4 aa = {0.f, 0.f, 0.f, 0.f}, ab_ = {0.f, 0.f, 0.f, 0.f};
                FMA4(aa, w0, xa0); FMA4(aa, w1, xa1); FMA4(aa, w2, xa2); FMA4(aa, w3, ha);
                FMA4(ab_, w0, xb0); FMA4(ab_, w1, xb1); FMA4(ab_, w2, xb2); FMA4(ab_, w3, hb);
                float sa = wred64(aa.x + aa.y + aa.z + aa.w);
                float sb = wred64(ab_.x + ab_.y + ab_.z + ab_.w);
                if (lane == 0) {
                    s_g[r] = sa + s_bias[r];
                    s_g[32 + r] = sb + s_bias[r];
                }
            }
            __syncthreads();
            if (tid < 16) {
                int el = tid >> 3, d = tid & 7;
                int base = el * 32;
                float gi = s_g[base + d], gf = s_g[base + 8 + d];
                float gg = s_g[base + 16 + d], go = s_g[base + 24 + d];
                float cv = sigf(gf) * s_c[tid] + sigf(gi) * tanhf(gg);
                s_c[tid] = cv;
                float hv = sigf(go) * tanhf(cv);
                st_co(Hbg + (size_t)(e0 + el) * Hh + db + d, hv);
            }
        }
        gbar(cnt, ++barnum * 32);

        // ---------- Phase T1: waves 0,1 = stack el0/el1; waves 2,3 = buffer el0/el1 ----------
        {
            int el = wave & 1;
            int e = e0 + el;
            float h0, h1, h2, h3;
            const float* hb = Hbg + (size_t)e * Hh + lane;
            ld_co_f1x4(hb, hb + 64, hb + 128, hb + 192, h0, h1, h2, h3);
            if (wave < 2) {           // stage h for next L
                s_h[el * 256 + lane] = h0;       s_h[el * 256 + 64 + lane] = h1;
                s_h[el * 256 + 128 + lane] = h2; s_h[el * 256 + 192 + lane] = h3;
            }
            float lg0 = h0 * aw[lane] + h1 * aw[64 + lane] + h2 * aw[128 + lane] + h3 * aw[192 + lane];
            float lg1 = h0 * aw[256 + lane] + h1 * aw[320 + lane] + h2 * aw[384 + lane] + h3 * aw[448 + lane];
            lg0 = wred64(lg0) + ab[0];
            lg1 = wred64(lg1) + ab[1];
            float a_r = 1.0f / (1.0f + expf(10.0f * (lg1 - lg0)));
            float a_s = 1.0f / (1.0f + expf(10.0f * (lg0 - lg1)));

            if (wave < 2) {
                // ----- stack pop scan (sole owner of s_s[el]/sw[el]/pw[el]) -----
                int m0 = lane * 4;
                int sb_ = el * Mp;
                float v0 = (m0     < Mm) ? s_s[sb_ + m0]     : 0.0f;
                float v1 = (m0 + 1 < Mm) ? s_s[sb_ + m0 + 1] : 0.0f;
                float v2 = (m0 + 2 < Mm) ? s_s[sb_ + m0 + 2] : 0.0f;
                float v3 = (m0 + 3 < Mm) ? s_s[sb_ + m0 + 3] : 0.0f;
                float c1 = v0 + v1, c2 = c1 + v2, c3 = c2 + v3;
                float inc = c3;
                #pragma unroll
                for (int off = 1; off < 64; off <<= 1) {
                    float u = __shfl_up(inc, off, 64);
                    if (lane >= off) inc += u;
                }
                float ex = inc - c3;
                float Pv[4]  = {ex + v0, ex + c1, ex + c2, ex + c3};
                float Pp[4]  = {ex, ex + v0, ex + c1, ex + c2};
                float vv_[4] = {v0, v1, v2, v3};
                float sn[4];
                #pragma unroll
                for (int i = 0; i < 4; i++) {
                    int m = m0 + i;
                    float w1 = fminf(Pv[i], a_r) - fminf(Pp[i], a_r);
                    float wt = fminf(Pv[i], 1.0f + a_r) - fminf(Pp[i], 1.0f + a_r);
                    float s2 = vv_[i] - wt;
                    if (m == idx)  s2 = a_r;
                    if (m == idx2) s2 = a_s;
                    sn[i] = s2;
                    if (m < Mm) {
                        sw1[sb_ + m] = w1;
                        sw2[sb_ + m] = wt - w1;
                        s_s[sb_ + m] = s2;
                    } else if (m < Mp) {
                        sw1[sb_ + m] = 0.0f; sw2[sb_ + m] = 0.0f;
                    }
                }
                // ----- stack push scan (alpha=1) on updated s; pw FULL -----
                float d1 = sn[0] + sn[1], d2 = d1 + sn[2], d3 = d2 + sn[3];
                float inc2 = d3;
                #pragma unroll
                for (int off = 1; off < 64; off <<= 1) {
                    float u = __shfl_up(inc2, off, 64);
                    if (lane >= off) inc2 += u;
                }
                float ex2 = inc2 - d3;
                float Qv[4] = {ex2 + sn[0], ex2 + d1, ex2 + d2, ex2 + d3};
                float Qp[4] = {ex2, ex2 + sn[0], ex2 + d1, ex2 + d2};
                #pragma unroll
                for (int i = 0; i < 4; i++) {
                    int m = m0 + i;
                    if (m < Mm) {
                        float w1e = fminf(Qv[i], 1.0f) - fminf(Qp[i], 1.0f);
                        pw1[sb_ + m] = w1e;
                        pw2[sb_ + m] = (fminf(Qv[i], 2.0f) - fminf(Qp[i], 2.0f)) - w1e;
                    } else if (m < Mp) {
                        pw1[sb_ + m] = 0.0f; pw2[sb_ + m] = 0.0f;
                    }
                }
            } else {
                // ----- buffer scans + dots (sole owner of s_sb[el]/s_wb[el]/s_wbe[el]) -----
                float sbv = (lane < Ss) ? s_sb[el * Ss + lane] : 0.0f;
                float Pb = wave_iscan(sbv, lane);
                float wb = fminf(Pb, a_s) - fminf(Pb - sbv, a_s);
                float sbn = sbv - wb;
                float Pb2 = wave_iscan(sbn, lane);
                float wbe = fminf(Pb2, 1.0f) - fminf(Pb2 - sbn, 1.0f);
                if (lane < Ss) {
                    s_sb[el * Ss + lane] = sbn;
                    s_wb[el * Ss + lane] = wb;
                    s_wbe[el * Ss + lane] = wbe;
                }
                float abf = 0.0f, axb = 0.0f;
                #pragma unroll
                for (int j = 0; j < 6; j++) {
                    int s = mg * 6 + j;
                    float be = s_B[el * 384 + s * 8 + dl8];
                    abf = fmaf(s_wb[el * Ss + s], be, abf);
                    axb = fmaf(s_wbe[el * Ss + s], be, axb);
                }
                abf = wred_mg(abf); axb = wred_mg(axb);
                if (lane < 8) {
                    s_V[el * (Mp * 8) + idx2 * 8 + dl8] = abf;  // pop reads see weight 0
                    st_co(XTg + (size_t)e * H3 + db + dl8, axb);
                }
            }
            __syncthreads();
            if (wave < 2) {           // pop V-loops: r1/r2 per element
                float a1 = 0.0f, a2 = 0.0f;
                #pragma unroll 5
                for (int k = 0; k < 25; k++) {
                    int m = mg * 25 + k;              // 0..199; pads zero
                    float vv = s_V[el * (Mp * 8) + m * 8 + dl8];
                    a1 = fmaf(sw1[el * Mp + m], vv, a1);
                    a2 = fmaf(sw2[el * Mp + m], vv, a2);
                }
                a1 = wred_mg(a1); a2 = wred_mg(a2);
                if (lane < 8) {
                    st_co(R1g + (size_t)e * Hh + db + dl8, a1);
                    st_co(R2g + (size_t)e * Hh + db + dl8, a2);
                }
            }
        }
        gbar(cnt, ++barnum * 32);

        // ---------- Phase T2: stage r1/r2 (both el), dual tree matvec, combine, push ----------
        {
            {
                int part = tid >> 6, r = tid & 63;    // 0:el0-r1 1:el0-r2 2:el1-r1 3:el1-r2
                int el = part >> 1;
                vf4 v;
                if (part & 1) {
                    ld_co_v4_1((const vf4*)R2g + (size_t)(e0 + el) * 64 + r, v);
                    ((vf4*)s_r2)[el * 64 + r] = v;
                } else {
                    ld_co_v4_1((const vf4*)R1g + (size_t)(e0 + el) * 64 + r, v);
                    ((vf4*)s_r1)[el * 64 + r] = v;
                }
            }
            __syncthreads();
            const vf4* sr14 = (const vf4*)s_r1;
            const vf4* sr24 = (const vf4*)s_r2;
            vf4 r1a = sr14[lane], r2a = sr24[lane];
            vf4 r1b = sr14[64 + lane], r2b = sr24[64 + lane];
            #pragma unroll 2
            for (int p = 0; p < 10; p++) {
                int r = wave * 10 + p;                 // 40 rows over 4 waves
                int row = ((r >> 3) << 8) + db + (r & 7);
                const vf4* wl = (const vf4*)tlw + (size_t)row * 64;
                const vf4* wr = (const vf4*)trw + (size_t)row * 64;
                vf4 u = wl[lane], v = wr[lane];
                vf4 aa = {0.f, 0.f, 0.f, 0.f}, ab_ = {0.f, 0.f, 0.f, 0.f};
                FMA4(aa, u, r1a); FMA4(aa, v, r2a);
                FMA4(ab_, u, r1b); FMA4(ab_, v, r2b);
                float sa = wred64(aa.x + aa.y + aa.z + aa.w);
                float sb = wred64(ab_.x + ab_.y + ab_.z + ab_.w);
                if (lane == 0) {
                    s_tg[r] = sa + s_tbias[r];
                    s_tg[40 + r] = sb + s_tbias[r];
                }
            }
            __syncthreads();
            if (tid < 16) {
                int el = tid >> 3, d = tid & 7;
                int base = el * 40;
                float ta  = s_tg[base + d];
                float ti  = s_tg[base + 8 + d];
                float tf1 = s_tg[base + 16 + d];
                float tf2 = s_tg[base + 24 + d];
                float to  = s_tg[base + 32 + d];
                float r1d = s_r1[el * 256 + db + d];
                float r2d = s_r2[el * 256 + db + d];
                float ct = tanhf(ta) * sigf(ti) + sigf(tf1) * r1d + sigf(tf2) * r2d;
                s_V[el * (Mp * 8) + idx * 8 + d] = sigf(to) * tanhf(ct);
            }
            __syncthreads();
            if (wave < 2) {           // push V-loops over fully-updated V
                int el = wave, e = e0 + el;
                float x1 = 0.0f, x2 = 0.0f;
                #pragma unroll 5
                for (int k = 0; k < 25; k++) {
                    int m = mg * 25 + k;
                    float vv = s_V[el * (Mp * 8) + m * 8 + dl8];
                    x1 = fmaf(pw1[el * Mp + m], vv, x1);
                    x2 = fmaf(pw2[el * Mp + m], vv, x2);
                }
                x1 = wred_mg(x1); x2 = wred_mg(x2);
                if (lane < 8) {
                    st_co(XTg + (size_t)e * H3 + 256 + db + dl8, x1);
                    st_co(XTg + (size_t)e * H3 + 512 + db + dl8, x2);
                }
            }
        }
        gbar(cnt, ++barnum * 32);
    }

    // ================= MLP head =================
    {   // layer 0: input = XT[:, 256:512], dual element; rows q8*32..+31
        if (tid < 128) {
            int el = tid >> 6, r = tid & 63;
            vf4 v;
            ld_co_v4_1((const vf4*)XTg + (size_t)(e0 + el) * 192 + 64 + r, v);
            ((vf4*)s_y)[el * 64 + r] = v;
        }
        __syncthreads();
        vf4 xina = ((const vf4*)s_y)[lane];
        vf4 xinb = ((const vf4*)s_y)[64 + lane];
        #pragma unroll 2
        for (int p = 0; p < 8; p++) {
            int row = q8 * 32 + wave * 8 + p;
            vf4 wv = ((const vf4*)l0w)[(size_t)row * 64 + lane];
            vf4 aa = {0.f, 0.f, 0.f, 0.f}, ab_ = {0.f, 0.f, 0.f, 0.f};
            FMA4(aa, wv, xina); FMA4(ab_, wv, xinb);
            float sa = wred64(aa.x + aa.y + aa.z + aa.w);
            float sb = wred64(ab_.x + ab_.y + ab_.z + ab_.w);
            if (lane == 0) {
                st_co(Y0g + (size_t)e0 * MLPD + row, fmaxf(sa + l0b[row], 0.0f));
                st_co(Y0g + (size_t)(e0 + 1) * MLPD + row, fmaxf(sb + l0b[row], 0.0f));
            }
        }
    }
    gbar(cnt, ++barnum * 32);
    {   // layer 1: K=1024, dual element
        for (int i = tid; i < 512; i += NTHR) {
            int el = i >> 8, r = i & 255;
            vf4 v;
            ld_co_v4_1((const vf4*)Y0g + (size_t)(e0 + el) * 256 + r, v);
            ((vf4*)s_y)[el * 256 + r] = v;
        }
        __syncthreads();
        const vf4* sy4 = (const vf4*)s_y;
        vf4 ya0 = sy4[lane], ya1 = sy4[64 + lane], ya2 = sy4[128 + lane], ya3 = sy4[192 + lane];
        vf4 yb0 = sy4[256 + lane], yb1 = sy4[320 + lane], yb2 = sy4[384 + lane], yb3 = sy4[448 + lane];
        #pragma unroll 2
        for (int p = 0; p < 8; p++) {
            int row = q8 * 32 + wave * 8 + p;
            const vf4* w = (const vf4*)l1w + (size_t)row * 256;
            vf4 w0 = w[lane], w1 = w[64 + lane], w2 = w[128 + lane], w3 = w[192 + lane];
            vf4 aa = {0.f, 0.f, 0.f, 0.f}, ab_ = {0.f, 0.f, 0.f, 0.f};
            FMA4(aa, w0, ya0); FMA4(aa, w1, ya1); FMA4(aa, w2, ya2); FMA4(aa, w3, ya3);
            FMA4(ab_, w0, yb0); FMA4(ab_, w1, yb1); FMA4(ab_, w2, yb2); FMA4(ab_, w3, yb3);
            float sa = wred64(aa.x + aa.y + aa.z + aa.w);
            float sb = wred64(ab_.x + ab_.y + ab_.z + ab_.w);
            if (lane == 0) {
                st_co(Y1g + (size_t)e0 * MLPD + row, fmaxf(sa + l1b[row], 0.0f));
                st_co(Y1g + (size_t)(e0 + 1) * MLPD + row, fmaxf(sb + l1b[row], 0.0f));
            }
        }
    }
    gbar(cnt, ++barnum * 32);
    if (q8 < 2) {  // layer 2: block (ep, q8=el) handles element e0+q8
        int e = e0 + q8;
        {
            vf4 v;
            ld_co_v4_1((const vf4*)Y1g + (size_t)e * 256 + tid, v);
            ((vf4*)s_y)[tid] = v;
        }
        __syncthreads();
        if (tid < 192) {
            int r = tid >> 6;
            const vf4* w = (const vf4*)l2w + (size_t)r * 256;
            vf4 acc = {0.f, 0.f, 0.f, 0.f};
            #pragma unroll
            for (int j = 0; j < 4; j++) {
                vf4 wv = w[lane + j * 64], yv = ((const vf4*)s_y)[lane + j * 64];
                FMA4(acc, wv, yv);
            }
            float sv = wred64(acc.x + acc.y + acc.z + acc.w);
            if (lane == 0) out[e * 3 + r] = sv + l2b[r];
        }
    }
}

extern "C" void kernel_launch(void* const* d_in, const int* in_sizes, int n_in,
                              void* d_out, int out_size, void* d_ws, size_t ws_size,
                              hipStream_t stream) {
    (void)in_sizes; (void)n_in; (void)out_size; (void)ws_size;
    (void)hipMemsetAsync(d_ws, 0, 4096, stream);  // 32 group counters x 128B

    const int*   x_   = (const int*)d_in[0];
    const float* emb  = (const float*)d_in[1];
    const float* wih  = (const float*)d_in[2];
    const float* whh  = (const float*)d_in[3];
    const float* bih  = (const float*)d_in[4];
    const float* bhh  = (const float*)d_in[5];
    const float* aw   = (const float*)d_in[6];
    const float* ab   = (const float*)d_in[7];
    const float* tlw  = (const float*)d_in[8];
    const float* tlb  = (const float*)d_in[9];
    const float* trw  = (const float*)d_in[10];
    const float* trb  = (const float*)d_in[11];
    const float* l0w  = (const float*)d_in[12];
    const float* l0b  = (const float*)d_in[13];
    const float* l1w  = (const float*)d_in[14];
    const float* l1b  = (const float*)d_in[15];
    const float* l2w  = (const float*)d_in[16];
    const float* l2b  = (const float*)d_in[17];

    float* wsf = (float*)((char*)d_ws + 4096);
    unsigned* bar = (unsigned*)d_ws;

    spinn_kernel<<<dim3(NBLK), dim3(NTHR), 0, stream>>>(
        x_, emb, wih, whh, bih, bhh, aw, ab, tlw, tlb, trw, trb,
        l0w, l0b, l1w, l1b, l2w, l2b, (float*)d_out, wsf, bar);
}